// Round 4
// baseline (186.522 us; speedup 1.0000x reference)
//
#include <hip/hip_runtime.h>
#include <math.h>

// GMM score, rescaled: out_j = (E_w[td] - x_j) / sigma2_j
// w_i = exp(-0.5 (td_i - x_j)^2 / sigma2_j), sigma2_j = (exp(2 t_j ln25)-1)/(2 ln25)
//
// Fitted model (R1-R3): dur = 41us harness ws-poison (fixed, 256MiB fill)
//   + gmm_partial + gmm_final(~2.5us) + ~8.5us dispatch gaps.
// R2/R3 findings: v_exp_f32 occupies the SIMD issue port ~16cyc (no VALU/trans
// overlap; JPT=1 vs 2 identical). Partial floor = (4 ops @2 + 1 exp @16)
// = 24 cyc/elem/j -> 41.0us; measured 40.8us => AT FLOOR. Software exp2
// (R3) needs >=9 FLOP-ops ~18cyc + scalar range ops -> regression (73us).
// REVERTED to HW exp.
// R4 (this round): fuse the final reduction into gmm_partial. Last-arriving
// block per j-column reduces the column (device-scope fences + init-free
// CAS magic-tag counter, since ws is poisoned). Removes gmm_final dispatch
// + 1 gap. Prediction: total 92.8 -> ~87-89us; FETCH_SIZE ~4.5MB on fused.

typedef float v2f __attribute__((ext_vector_type(2)));

#define BLK   256
#define JPT   2      // outputs per thread
#define CH    512    // train elements per slice (2 KB LDS); S = N/CH = 32

#if __has_builtin(__builtin_amdgcn_exp2f)
#define EXP2(x) __builtin_amdgcn_exp2f(x)
#else
#define EXP2(x) exp2f(x)
#endif

#define CNT_MAGIC 0xA5F00D21ull

__device__ __forceinline__ float sigma2_of(float tj) {
  const float TWO_LOG_S = 6.4377516497364011f;   // 2*ln(25)
  return (__expf(TWO_LOG_S * tj) - 1.0f) / TWO_LOG_S;
}

// Init-free column-arrival counter on poisoned memory: first arriver installs
// (MAGIC<<32)|1 via CAS; later arrivers fetch_add(1). Returns this block's
// arrival ordinal (1..S). Poison collision prob ~2^-32 per column.
__device__ __forceinline__ unsigned int col_arrive(unsigned long long* c) {
  unsigned long long cur =
      __hip_atomic_load(c, __ATOMIC_RELAXED, __HIP_MEMORY_SCOPE_AGENT);
  while ((cur >> 32) != CNT_MAGIC) {
    unsigned long long expected = cur;
    unsigned long long desired = (CNT_MAGIC << 32) | 1ull;
    if (__hip_atomic_compare_exchange_strong(
            c, &expected, desired, __ATOMIC_ACQ_REL, __ATOMIC_RELAXED,
            __HIP_MEMORY_SCOPE_AGENT))
      return 1u;
    cur = expected;   // CAS lost: expected now holds the installed value
  }
  unsigned long long old =
      __hip_atomic_fetch_add(c, 1ull, __ATOMIC_ACQ_REL, __HIP_MEMORY_SCOPE_AGENT);
  return (unsigned int)(old & 0xFFFFFFFFull) + 1u;
}

__device__ __forceinline__ float ws_load(const float* p) {
  // Agent-scope relaxed load: bypasses L1/L2 so cross-XCD partials are fresh.
  return __hip_atomic_load(p, __ATOMIC_RELAXED, __HIP_MEMORY_SCOPE_AGENT);
}

template <bool ATOMIC>
__launch_bounds__(BLK, 4)
__global__ void gmm_partial(const float* __restrict__ x,
                            const float* __restrict__ t,
                            const float* __restrict__ td,
                            float* __restrict__ ws,
                            float* __restrict__ out,
                            int N, int B) {
  __shared__ float lds[CH];
  __shared__ int is_last;
  const int tid  = threadIdx.x;
  const int bx   = blockIdx.x;
  const int j0   = bx * (BLK * JPT) + tid;   // first output index
  const int j1   = j0 + BLK;                 // second output index
  const int s    = blockIdx.y;               // N-slice
  const int S    = gridDim.y;
  const int base = s * CH;

  for (int i = tid; i < CH; i += BLK) {
    int gi = base + i;
    // pad -> d^2 = inf -> exp2(-inf) = 0 (weightless)
    lds[i] = (gi < N) ? td[gi] : 1e30f;
  }

  const float HALF_LOG2E = 0.72134752044448170f;  // 0.5 * log2(e)
  float r0 = 0.0f, y0 = 0.0f, r1 = 0.0f, y1 = 0.0f;
  if (j0 < B) {
    float s2 = sigma2_of(t[j0]);
    r0 = __fsqrt_rn(HALF_LOG2E / s2);   // d = (td - x)*r ; arg = -d^2
    y0 = x[j0] * r0;
  }
  if (j1 < B) {
    float s2 = sigma2_of(t[j1]);
    r1 = __fsqrt_rn(HALF_LOG2E / s2);
    y1 = x[j1] * r1;
  }
  __syncthreads();

  const v2f rv0  = {r0, r0};
  const v2f nyv0 = {-y0, -y0};
  const v2f rv1  = {r1, r1};
  const v2f nyv1 = {-y1, -y1};

  // per-j accumulators: 2 num + 2 den (v2f) each
  v2f n00 = {0.f, 0.f}, n01 = {0.f, 0.f}, d00 = {0.f, 0.f}, d01 = {0.f, 0.f};
  v2f n10 = {0.f, 0.f}, n11 = {0.f, 0.f}, d10 = {0.f, 0.f}, d11 = {0.f, 0.f};

  const float4* l4 = (const float4*)lds;   // ds_read_b128 broadcast, conflict-free
  const int iters = CH >> 3;               // 8 td elements per iteration

#define GROUP(v, naccA, daccA, naccB, daccB)                            \
  {                                                                     \
    v2f dA = __builtin_elementwise_fma(v, rv0, nyv0);                   \
    v2f dB = __builtin_elementwise_fma(v, rv1, nyv1);                   \
    v2f qA = dA * dA;                                                   \
    v2f qB = dB * dB;                                                   \
    v2f pA, pB;                                                         \
    pA.x = EXP2(-qA.x); pA.y = EXP2(-qA.y);                             \
    pB.x = EXP2(-qB.x); pB.y = EXP2(-qB.y);                             \
    daccA += pA;                                                        \
    daccB += pB;                                                        \
    naccA = __builtin_elementwise_fma(pA, v, naccA);                    \
    naccB = __builtin_elementwise_fma(pB, v, naccB);                    \
  }

  #pragma unroll 2
  for (int i = 0; i < iters; ++i) {
    float4 v0 = l4[2 * i];
    float4 v1 = l4[2 * i + 1];
    v2f va = {v0.x, v0.y}, vb = {v0.z, v0.w};
    v2f vc = {v1.x, v1.y}, vd = {v1.z, v1.w};
    GROUP(va, n00, d00, n10, d10)
    GROUP(vb, n01, d01, n11, d11)
    GROUP(vc, n00, d00, n10, d10)
    GROUP(vd, n01, d01, n11, d11)
  }
#undef GROUP

  v2f numv0 = n00 + n01, denv0 = d00 + d01;
  v2f numv1 = n10 + n11, denv1 = d10 + d11;
  float num0 = numv0.x + numv0.y, den0 = denv0.x + denv0.y;
  float num1 = numv1.x + numv1.y, den1 = denv1.x + denv1.y;

  if (ATOMIC) {
    if (j0 < B) {
      atomicAdd(&ws[j0], num0);
      atomicAdd(&ws[B + j0], den0);
    }
    if (j1 < B) {
      atomicAdd(&ws[j1], num1);
      atomicAdd(&ws[B + j1], den1);
    }
    return;
  }

  if (j0 < B) {
    ws[(size_t)s * B + j0]       = num0;   // num partials: [S][B]
    ws[(size_t)(S + s) * B + j0] = den0;   // den partials: [S][B]
  }
  if (j1 < B) {
    ws[(size_t)s * B + j1]       = num1;
    ws[(size_t)(S + s) * B + j1] = den1;
  }

  // ---- fused final reduction: last-arriving block of this j-column ----
  __threadfence();            // release this block's partials to device scope
  __syncthreads();            // all stores + fences done before the arrive
  if (tid == 0) {
    unsigned long long* cnt =
        (unsigned long long*)(ws + (size_t)2 * S * B);
    unsigned int arrived = col_arrive(&cnt[bx]);
    is_last = (arrived == (unsigned int)S) ? 1 : 0;
  }
  __syncthreads();
  if (!is_last) return;

  // This block saw all S arrivals (acquire via the atomic). Reduce the column.
  #pragma unroll
  for (int k = 0; k < JPT; ++k) {
    int j = j0 + k * BLK;
    if (j >= B) continue;
    float num = 0.f, den = 0.f;
    for (int ss = 0; ss < S; ++ss) {
      num += ws_load(&ws[(size_t)ss * B + j]);
      den += ws_load(&ws[(size_t)(S + ss) * B + j]);
    }
    float sigma2 = sigma2_of(t[j]);
    float evals = (den == 0.0f) ? 0.0f : (num / den);   // reference's guard
    out[j] = (evals - x[j]) / sigma2;
  }
}

__global__ void gmm_final_serial(const float* __restrict__ x,
                                 const float* __restrict__ t,
                                 const float* __restrict__ ws,
                                 float* __restrict__ out, int B, int S) {
  int j = blockIdx.x * blockDim.x + threadIdx.x;
  if (j >= B) return;
  float num = 0.f, den = 0.f;
  for (int s = 0; s < S; ++s) {
    num += ws[(size_t)s * B + j];
    den += ws[(size_t)(S + s) * B + j];
  }
  float sigma2 = sigma2_of(t[j]);
  float evals = (den == 0.0f) ? 0.0f : (num / den);
  out[j] = (evals - x[j]) / sigma2;
}

__global__ void zero_kernel(float* __restrict__ p, int n) {
  int i = blockIdx.x * blockDim.x + threadIdx.x;
  if (i < n) p[i] = 0.0f;
}

extern "C" void kernel_launch(void* const* d_in, const int* in_sizes, int n_in,
                              void* d_out, int out_size, void* d_ws, size_t ws_size,
                              hipStream_t stream) {
  const float* x  = (const float*)d_in[0];
  const float* t  = (const float*)d_in[1];
  const float* td = (const float*)d_in[2];
  float* out = (float*)d_out;
  float* ws  = (float*)d_ws;

  const int B = in_sizes[0];
  const int N = in_sizes[2];

  const int S = (N + CH - 1) / CH;                  // 32 for N=16384
  const int JBLK = BLK * JPT;                       // outputs per block = 512
  const int GX = (B + JBLK - 1) / JBLK;             // 32 columns
  size_t need = (size_t)2 * S * B * sizeof(float)   // 4 MB partials
              + (size_t)GX * sizeof(unsigned long long);  // arrival counters

  if (ws_size >= need) {
    dim3 grid(GX, S);                               // (32, 32) = 1024 blocks
    gmm_partial<false><<<grid, BLK, 0, stream>>>(x, t, td, ws, out, N, B);
  } else {
    // Fallback: zero + atomic accumulate + serial final (3 dispatches)
    int nzero = 2 * B;
    zero_kernel<<<(nzero + 255) / 256, 256, 0, stream>>>(ws, nzero);
    dim3 grid(GX, S);
    gmm_partial<true><<<grid, BLK, 0, stream>>>(x, t, td, ws, out, N, B);
    gmm_final_serial<<<(B + 255) / 256, 256, 0, stream>>>(x, t, ws, out, B, S);
  }
}

// Round 5
// 95.130 us; speedup vs baseline: 1.9607x; 1.9607x over previous
//
#include <hip/hip_runtime.h>
#include <math.h>

// GMM score, rescaled: out_j = (E_w[td] - x_j) / sigma2_j
// w_i = exp(-0.5 (td_i - x_j)^2 / sigma2_j), sigma2_j = (exp(2 t_j ln25)-1)/(2 ln25)
//
// Model (R1-R4): dur = 41us harness ws-poison fill (fixed, 256MiB @83% HBM)
//   + compute + gaps. Compute floor: 1 exp (16-20cyc, issue-serial) + 4 pk ops
//   (8cyc) per 2 (elem,j) evals => ~41us at >=4 waves/SIMD. R2 hit it (40.8).
// R3 (sw exp2 poly): 73us REGRESSION -- v_exp_f32 cannot be beaten in sw.
// R4 (fence-based fused reduction): 140us REGRESSION -- per-block device-scope
//   __threadfence = cross-XCD L2 writeback x1024 blocks ~ +100us stall.
// R5 (this round): single-dispatch, ZERO inter-block communication.
//   Each block owns 16 j's outright and covers ALL of N: 256 thr = 16 j-lanes
//   x 16 N-windows of N/16=1024. Cross-window combine = in-block LDS reduce.
//   Same eval instruction mix, same 4 waves/SIMD occupancy as R2's floor
//   config. td read from global (64KB, L1/L2-resident; 16-way lane redundancy
//   collapses in the coalescer). No ws, no atomics, no fences, 1 dispatch.
// Prediction: kernel 42-44us, WRITE_SIZE ~64KB, total ~86-88us.
// Revert trigger: fused kernel >=50us -> back to R2 two-dispatch.

typedef float v2f __attribute__((ext_vector_type(2)));

#define BLK   256
#define JB    16     // j's per block
#define PARTS 16     // N-windows per block (BLK/JB)

#if __has_builtin(__builtin_amdgcn_exp2f)
#define EXP2(x) __builtin_amdgcn_exp2f(x)
#else
#define EXP2(x) exp2f(x)
#endif

__device__ __forceinline__ float sigma2_of(float tj) {
  const float TWO_LOG_S = 6.4377516497364011f;   // 2*ln(25)
  return (__expf(TWO_LOG_S * tj) - 1.0f) / TWO_LOG_S;
}

__launch_bounds__(BLK, 4)
__global__ void gmm_fused(const float* __restrict__ x,
                          const float* __restrict__ t,
                          const float* __restrict__ td,
                          float* __restrict__ out,
                          int N, int B) {
  __shared__ float nbuf[PARTS * JB];
  __shared__ float dbuf[PARTS * JB];

  const int tid  = threadIdx.x;
  const int jl   = tid & (JB - 1);      // j-lane within block
  const int part = tid >> 4;            // N-window index (0..15)
  const int j    = blockIdx.x * JB + jl;

  // Window [lo, hi) of N for this thread's partial sums.
  const int W  = (N + PARTS - 1) / PARTS;   // 1024 for N=16384
  const int lo = part * W;
  const int hi = (lo + W < N) ? (lo + W) : N;

  float r = 0.0f, y = 0.0f;
  if (j < B) {
    const float HALF_LOG2E = 0.72134752044448170f;  // 0.5 * log2(e)
    float s2 = sigma2_of(t[j]);
    r = __fsqrt_rn(HALF_LOG2E / s2);   // d = (td - x)*r ; arg = -d^2 (base-2)
    y = x[j] * r;
  }

  const v2f rv  = {r, r};
  const v2f nyv = {-y, -y};

  v2f n0 = {0.f, 0.f}, n1 = {0.f, 0.f};
  v2f d0 = {0.f, 0.f}, d1 = {0.f, 0.f};

#define GROUP(v, nacc, dacc)                                            \
  {                                                                     \
    v2f dd = __builtin_elementwise_fma(v, rv, nyv);                     \
    v2f qq = dd * dd;                                                   \
    v2f pp;                                                             \
    pp.x = EXP2(-qq.x); pp.y = EXP2(-qq.y);                             \
    dacc += pp;                                                         \
    nacc = __builtin_elementwise_fma(pp, v, nacc);                      \
  }

  int i = lo;
  // fast path: 8 elements per iteration via two float4 loads (lo is
  // 16B-aligned when W%4==0, which holds for N%64==0; guarded otherwise)
  if (((W & 3) == 0)) {
    const int hi8 = lo + ((hi - lo) & ~7);
    #pragma unroll 2
    for (; i < hi8; i += 8) {
      float4 v0 = *(const float4*)(td + i);
      float4 v1 = *(const float4*)(td + i + 4);
      v2f va = {v0.x, v0.y}, vb = {v0.z, v0.w};
      v2f vc = {v1.x, v1.y}, vd = {v1.z, v1.w};
      GROUP(va, n0, d0)
      GROUP(vb, n1, d1)
      GROUP(vc, n0, d0)
      GROUP(vd, n1, d1)
    }
  }
  // tail / unaligned fallback: scalar-pair loop with pad semantics
  for (; i < hi; i += 2) {
    float e0 = td[i];
    float e1 = (i + 1 < hi) ? td[i + 1] : 1e30f;   // pad -> exp2(-inf) = 0
    v2f v = {e0, e1};
    GROUP(v, n0, d0)
  }
#undef GROUP

  v2f numv = n0 + n1;
  v2f denv = d0 + d1;
  nbuf[part * JB + jl] = numv.x + numv.y;
  dbuf[part * JB + jl] = denv.x + denv.y;
  __syncthreads();

  // Final combine: 16 threads, each sums 16 window-partials for its j.
  if (tid < JB && (blockIdx.x * JB + tid) < B) {
    const int jj = blockIdx.x * JB + tid;
    float num = 0.f, den = 0.f;
    #pragma unroll
    for (int p = 0; p < PARTS; ++p) {
      num += nbuf[p * JB + tid];   // stride JB: lanes hit distinct banks
      den += dbuf[p * JB + tid];
    }
    float sigma2 = sigma2_of(t[jj]);
    float evals = (den == 0.0f) ? 0.0f : (num / den);   // reference's guard
    out[jj] = (evals - x[jj]) / sigma2;
  }
}

extern "C" void kernel_launch(void* const* d_in, const int* in_sizes, int n_in,
                              void* d_out, int out_size, void* d_ws, size_t ws_size,
                              hipStream_t stream) {
  const float* x  = (const float*)d_in[0];
  const float* t  = (const float*)d_in[1];
  const float* td = (const float*)d_in[2];
  float* out = (float*)d_out;
  (void)d_ws; (void)ws_size;

  const int B = in_sizes[0];
  const int N = in_sizes[2];

  const int GX = (B + JB - 1) / JB;   // 1024 blocks for B=16384
  gmm_fused<<<GX, BLK, 0, stream>>>(x, t, td, out, N, B);
}

// Round 6
// 92.382 us; speedup vs baseline: 2.0190x; 1.0297x over previous
//
#include <hip/hip_runtime.h>
#include <math.h>

// GMM score, rescaled: out_j = (E_w[td] - x_j) / sigma2_j
// w_i = exp(-0.5 (td_i - x_j)^2 / sigma2_j), sigma2_j = (exp(2 t_j ln25)-1)/(2 ln25)
//
// Model (R1-R5): dur = 41us harness ws-poison fill (fixed) + kernel + gap(~4.5us
// single-dispatch). Compute floor: 1 v_exp_f32 (16-20cyc, issue-serial) + 4 pk
// ops per 2 evals => ~41us at 4 waves/SIMD (R2 measured 40.8us).
// R3 sw-exp2: 73us REGRESSION. R4 fence-fusion: 140us REGRESSION.
// R5 global-load fused: kernel 49.6us (+9us global-load stall vs LDS broadcast),
// but single-dispatch gap saving confirmed (~4.3us).
// R6 (this round): fused + LDS chunk delivery. Block owns 16 j's, covers all N
// in 8 chunks of 2048 staged in LDS (reg double-buffered, coalesced float4).
// Thread (jl,part): j = blk*16+jl, reads f4[part+16k] -> conflict-free
// broadcast ds_read_b128. In-block LDS reduce tail. No ws/atomics/fences.
// Prediction: kernel ~42-44us, VALUBusy >=60%, total ~87-89us.
// Revert trigger: kernel >=47us -> R2 two-dispatch was the floor (roofline).

typedef float v2f __attribute__((ext_vector_type(2)));

#define BLK   256
#define JB    16     // j's per block
#define PARTS 16     // N-part groups per block (BLK/JB)
#define CH    2048   // td elements per LDS chunk (8 KB)

#if __has_builtin(__builtin_amdgcn_exp2f)
#define EXP2(x) __builtin_amdgcn_exp2f(x)
#else
#define EXP2(x) exp2f(x)
#endif

__device__ __forceinline__ float sigma2_of(float tj) {
  const float TWO_LOG_S = 6.4377516497364011f;   // 2*ln(25)
  return (__expf(TWO_LOG_S * tj) - 1.0f) / TWO_LOG_S;
}

__device__ __forceinline__ float4 load_pad(const float* __restrict__ td,
                                           int gi, int N) {
  // pad -> d^2 = inf -> exp2(-inf) = 0 (weightless); num fma adds 0*big = 0
  if (gi + 3 < N) return *(const float4*)(td + gi);
  float4 v;
  v.x = (gi + 0 < N) ? td[gi + 0] : 1e30f;
  v.y = (gi + 1 < N) ? td[gi + 1] : 1e30f;
  v.z = (gi + 2 < N) ? td[gi + 2] : 1e30f;
  v.w = (gi + 3 < N) ? td[gi + 3] : 1e30f;
  return v;
}

__launch_bounds__(BLK, 4)
__global__ void gmm_fused(const float* __restrict__ x,
                          const float* __restrict__ t,
                          const float* __restrict__ td,
                          float* __restrict__ out,
                          int N, int B) {
  __shared__ float lds[CH];
  __shared__ float nbuf[PARTS * JB];
  __shared__ float dbuf[PARTS * JB];

  const int tid  = threadIdx.x;
  const int jl   = tid & (JB - 1);      // j-lane within block
  const int part = tid >> 4;            // N-part group (0..15)
  const int j    = blockIdx.x * JB + jl;

  float r = 0.0f, y = 0.0f;
  if (j < B) {
    const float HALF_LOG2E = 0.72134752044448170f;  // 0.5 * log2(e)
    float s2 = sigma2_of(t[j]);
    r = __fsqrt_rn(HALF_LOG2E / s2);   // d = (td - x)*r ; arg = -d^2 (base-2)
    y = x[j] * r;
  }

  const v2f rv  = {r, r};
  const v2f nyv = {-y, -y};

  // accumulators persist across chunks: 4 num + 4 den (v2f)
  v2f n0 = {0.f, 0.f}, n1 = {0.f, 0.f}, n2 = {0.f, 0.f}, n3 = {0.f, 0.f};
  v2f d0 = {0.f, 0.f}, d1 = {0.f, 0.f}, d2 = {0.f, 0.f}, d3 = {0.f, 0.f};

#define GROUP(v, nacc, dacc)                                            \
  {                                                                     \
    v2f dd = __builtin_elementwise_fma(v, rv, nyv);                     \
    v2f qq = dd * dd;                                                   \
    v2f pp;                                                             \
    pp.x = EXP2(-qq.x); pp.y = EXP2(-qq.y);                             \
    dacc += pp;                                                         \
    nacc = __builtin_elementwise_fma(pp, v, nacc);                      \
  }

  const int NC = (N + CH - 1) / CH;     // 8 chunks for N=16384
  const float4* l4 = (const float4*)lds;

  // register double-buffer: this thread stages f4 slots tid and tid+BLK
  float4 pA = load_pad(td, tid * 4, N);
  float4 pB = load_pad(td, (tid + BLK) * 4, N);

  for (int c = 0; c < NC; ++c) {
    // issue next chunk's loads early; vmcnt wait lands after compute
    float4 nA = pA, nB = pB;
    if (c + 1 < NC) {
      const int nb = (c + 1) * CH;
      nA = load_pad(td, nb + tid * 4, N);
      nB = load_pad(td, nb + (tid + BLK) * 4, N);
    }

    ((float4*)lds)[tid]       = pA;     // linear ds_write_b128
    ((float4*)lds)[tid + BLK] = pB;
    __syncthreads();

    // this thread's share: float4 groups g = part + 16k, k = 0..31
    #pragma unroll 4
    for (int k = 0; k < CH / 64; k += 2) {
      float4 v0 = l4[part + 16 * k];        // 4 distinct addrs/wave, 16-way
      float4 v1 = l4[part + 16 * k + 16];   //   broadcast, banks 0-15: clean
      v2f va = {v0.x, v0.y}, vb = {v0.z, v0.w};
      v2f vc = {v1.x, v1.y}, vd = {v1.z, v1.w};
      GROUP(va, n0, d0)
      GROUP(vb, n1, d1)
      GROUP(vc, n2, d2)
      GROUP(vd, n3, d3)
    }
    __syncthreads();   // LDS consumed; safe to overwrite next iter

    pA = nA;
    pB = nB;
  }
#undef GROUP

  v2f numv = (n0 + n1) + (n2 + n3);
  v2f denv = (d0 + d1) + (d2 + d3);
  nbuf[part * JB + jl] = numv.x + numv.y;
  dbuf[part * JB + jl] = denv.x + denv.y;
  __syncthreads();

  // Final combine: 16 threads, each sums 16 part-partials for its j.
  if (tid < JB && (blockIdx.x * JB + tid) < B) {
    const int jj = blockIdx.x * JB + tid;
    float num = 0.f, den = 0.f;
    #pragma unroll
    for (int p = 0; p < PARTS; ++p) {
      num += nbuf[p * JB + tid];   // lanes read consecutive floats: clean
      den += dbuf[p * JB + tid];
    }
    float sigma2 = sigma2_of(t[jj]);
    float evals = (den == 0.0f) ? 0.0f : (num / den);   // reference's guard
    out[jj] = (evals - x[jj]) / sigma2;
  }
}

extern "C" void kernel_launch(void* const* d_in, const int* in_sizes, int n_in,
                              void* d_out, int out_size, void* d_ws, size_t ws_size,
                              hipStream_t stream) {
  const float* x  = (const float*)d_in[0];
  const float* t  = (const float*)d_in[1];
  const float* td = (const float*)d_in[2];
  float* out = (float*)d_out;
  (void)d_ws; (void)ws_size;

  const int B = in_sizes[0];
  const int N = in_sizes[2];

  const int GX = (B + JB - 1) / JB;   // 1024 blocks for B=16384
  gmm_fused<<<GX, BLK, 0, stream>>>(x, t, td, out, N, B);
}